// Round 1
// baseline (224.488 us; speedup 1.0000x reference)
//
#include <hip/hip_runtime.h>
#include <hip/hip_bf16.h>

// out[r, 0:S]    = p = x[r, 0:S]
// out[r, S:2S]   = w[r] * selu(p) + x[r, S:2S]
// S = 4096, x is (S, 2S) fp32 row-major. Pure elementwise, memory-bound.
// One thread handles one float4 of p and the matching float4 of q.

#define SIZE 4096
#define HALF4 (SIZE / 4)          // 1024 float4 per half-row
#define ROW4  (2 * HALF4)         // 2048 float4 per full row

__global__ __launch_bounds__(256) void selu_residual_kernel(
    const float4* __restrict__ x4,
    const float* __restrict__ weight,
    float4* __restrict__ out4)
{
    const unsigned tid = blockIdx.x * blockDim.x + threadIdx.x;  // 0 .. SIZE*HALF4-1
    const unsigned row = tid >> 10;          // / HALF4
    const unsigned c   = tid & (HALF4 - 1);  // % HALF4

    const float w = weight[row];             // wave-uniform (64 lanes share a row)

    const float4 p = x4[row * ROW4 + c];
    const float4 q = x4[row * ROW4 + HALF4 + c];

    const float scale = 1.0507009873554804934f;
    const float alpha = 1.6732632423543772848f;

    float4 r;
    {
        float sp;
        sp = p.x > 0.0f ? scale * p.x : scale * alpha * (__expf(p.x) - 1.0f);
        r.x = w * sp + q.x;
        sp = p.y > 0.0f ? scale * p.y : scale * alpha * (__expf(p.y) - 1.0f);
        r.y = w * sp + q.y;
        sp = p.z > 0.0f ? scale * p.z : scale * alpha * (__expf(p.z) - 1.0f);
        r.z = w * sp + q.z;
        sp = p.w > 0.0f ? scale * p.w : scale * alpha * (__expf(p.w) - 1.0f);
        r.w = w * sp + q.w;
    }

    out4[row * ROW4 + c]         = p;   // pass-through half
    out4[row * ROW4 + HALF4 + c] = r;   // fused half
}

extern "C" void kernel_launch(void* const* d_in, const int* in_sizes, int n_in,
                              void* d_out, int out_size, void* d_ws, size_t ws_size,
                              hipStream_t stream) {
    const float4* x4     = (const float4*)d_in[0];
    const float*  weight = (const float*)d_in[1];
    float4*       out4   = (float4*)d_out;

    const int total_threads = SIZE * HALF4;       // 4096 * 1024 = 4,194,304
    const int block = 256;
    const int grid  = total_threads / block;      // 16384

    selu_residual_kernel<<<grid, block, 0, stream>>>(x4, weight, out4);
}

// Round 3
// 219.232 us; speedup vs baseline: 1.0240x; 1.0240x over previous
//
#include <hip/hip_runtime.h>
#include <hip/hip_bf16.h>

// out[r, 0:S]  = p = x[r, 0:S]
// out[r, S:2S] = w[r] * selu(p) + x[r, S:2S]
// S = 4096, x is (S, 2S) fp32 row-major. Pure elementwise, memory-bound.
//
// R3: same plan as R2 but with clang native vectors (ext_vector_type) so
// __builtin_nontemporal_load/store compiles. One block per row; each thread
// handles 4 float4-pairs, all 8 loads issued before any compute (4x MLP),
// nontemporal hints on streamed data (read-once / write-once).

#define SIZE  4096
#define HALF4 (SIZE / 4)          // 1024 float4 per half-row
#define ROW4  (2 * HALF4)         // 2048 float4 per full row

typedef float f32x4 __attribute__((ext_vector_type(4)));

__device__ __forceinline__ f32x4 selu_fma(f32x4 p, f32x4 q, float w) {
    const float scale = 1.0507009873554804934f;
    const float alpha = 1.6732632423543772848f;
    f32x4 r;
#pragma unroll
    for (int i = 0; i < 4; ++i) {
        float sp = p[i] > 0.0f ? scale * p[i]
                               : scale * alpha * (__expf(p[i]) - 1.0f);
        r[i] = w * sp + q[i];
    }
    return r;
}

__global__ __launch_bounds__(256) void selu_residual_kernel(
    const f32x4* __restrict__ x4,
    const float* __restrict__ weight,
    f32x4* __restrict__ out4)
{
    const unsigned row  = blockIdx.x;            // 0..4095
    const float    w    = weight[row];           // block-uniform scalar load
    const unsigned base = row * ROW4;

    f32x4 p[4], q[4];
    // Issue all 8 loads up front: 4 KiB/wave outstanding.
#pragma unroll
    for (int k = 0; k < 4; ++k) {
        const unsigned c = threadIdx.x + k * 256;
        p[k] = __builtin_nontemporal_load(&x4[base + c]);
        q[k] = __builtin_nontemporal_load(&x4[base + HALF4 + c]);
    }

#pragma unroll
    for (int k = 0; k < 4; ++k) {
        const unsigned c = threadIdx.x + k * 256;
        const f32x4 r = selu_fma(p[k], q[k], w);
        __builtin_nontemporal_store(p[k], &out4[base + c]);
        __builtin_nontemporal_store(r,    &out4[base + HALF4 + c]);
    }
}

extern "C" void kernel_launch(void* const* d_in, const int* in_sizes, int n_in,
                              void* d_out, int out_size, void* d_ws, size_t ws_size,
                              hipStream_t stream) {
    const f32x4* x4     = (const f32x4*)d_in[0];
    const float* weight = (const float*)d_in[1];
    f32x4*       out4   = (f32x4*)d_out;

    // One block per row: 4096 blocks x 256 threads; each thread does
    // 4 float4-pairs (1024 float4 per half-row / 256 threads).
    selu_residual_kernel<<<SIZE, 256, 0, stream>>>(x4, weight, out4);
}